// Round 3
// baseline (75.014 us; speedup 1.0000x reference)
//
#include <hip/hip_runtime.h>

// PCEN: EMA over time then (x / (M+eps)^alpha + delta)^r - delta^r
// x: [B=64, T=2048, F=128] float32, out same shape/type.
//
// EXACT block-level chunked scan (no warm-up approximation):
//   block = (b, 16-f tile) owns the full T=2048 sequence.
//   pass 1: 256 threads = 4 float4-groups x 64 chunks (L=32); each runs the
//           EMA from 0-init over its chunk (chunk 0 uses the exact m[0]=x[0]
//           rule), writes the chunk-end carry to LDS.
//   prefix: EMA is affine => m_end[c] = local_end[c] + a^L * m_in[c].
//           16 threads (one per scalar f) serially compose 64 carries.
//   pass 2: each thread re-runs its chunk with the exact carry-in and emits
//           PCEN output. Second read of x is L2/L3-hot (128 KB/block).

namespace {
constexpr int B = 64;
constexpr int T = 2048;
constexpr int F = 128;
constexpr int FT = 16;        // f per block
constexpr int NF4 = FT / 4;   // 4 float4 groups
constexpr int CH = 64;        // chunks per sequence
constexpr int L = T / CH;     // 32
constexpr float S = 0.025f;
constexpr float A1 = 0.975f;
constexpr float AL = 0.44478230849f;  // 0.975^32
constexpr float EPS = 1e-6f;
constexpr float ALPHA = 0.98f;
constexpr float DR = 1.1892071150027210667f;  // 2^0.25
}

__device__ __forceinline__ float pcen1(float xv, float m) {
    // x / (M+eps)^alpha == x * exp2(-alpha * log2(M+eps))
    float inv = exp2f(-ALPHA * log2f(m + EPS));
    float u   = fmaf(xv, inv, 2.0f);
    return sqrtf(sqrtf(u)) - DR;
}

__device__ __forceinline__ float4 pcen4(float4 xv, float4 m) {
    return make_float4(pcen1(xv.x, m.x), pcen1(xv.y, m.y),
                       pcen1(xv.z, m.z), pcen1(xv.w, m.w));
}

__device__ __forceinline__ void ema4(float4& m, float4 xv) {
    m.x = fmaf(A1, m.x, S * xv.x);
    m.y = fmaf(A1, m.y, S * xv.y);
    m.z = fmaf(A1, m.z, S * xv.z);
    m.w = fmaf(A1, m.w, S * xv.w);
}

__global__ __launch_bounds__(256) void pcen_kernel(const float* __restrict__ x,
                                                   float* __restrict__ out) {
    __shared__ float carry[CH][FT];
    __shared__ float inbuf[CH][FT];

    const int blk = blockIdx.x;          // 0..511
    const int b   = blk >> 3;
    const int ft  = (blk & 7) * FT;

    const int tid = threadIdx.x;
    const int f4  = tid & (NF4 - 1);     // 0..3
    const int c   = tid >> 2;            // 0..63

    const size_t base = ((size_t)b * T + (size_t)c * L) * F + ft + f4 * 4;
    const float4* px = (const float4*)(x + base);      // t-stride: F/4 = 32
    float4*       qo = (float4*)(out + base);

    // ---- pass 1: local EMA (0-init; chunk 0 exact) ----
    float4 m;
    if (c == 0) {
        m = px[0];                                      // m[0] = x[0]
        #pragma unroll 8
        for (int t = 1; t < L; ++t) { float4 xv = px[(size_t)t * (F / 4)]; ema4(m, xv); }
    } else {
        m = make_float4(0.f, 0.f, 0.f, 0.f);
        #pragma unroll 8
        for (int t = 0; t < L; ++t) { float4 xv = px[(size_t)t * (F / 4)]; ema4(m, xv); }
    }
    *(float4*)&carry[c][f4 * 4] = m;
    __syncthreads();

    // ---- prefix over chunks (16 scalar-f lanes) ----
    if (tid < FT) {
        const int f = tid;
        float me = carry[0][f];                         // exact end of chunk 0
        #pragma unroll 16
        for (int cc = 1; cc < CH; ++cc) {
            inbuf[cc][f] = me;                          // carry-in for chunk cc
            me = fmaf(AL, me, carry[cc][f]);            // m_end = a^L*m_in + local
        }
    }
    __syncthreads();

    // ---- pass 2: recompute with exact carry-in, emit PCEN ----
    if (c == 0) {
        float4 xv = px[0];
        float4 mm = xv;
        qo[0] = pcen4(xv, mm);
        #pragma unroll 8
        for (int t = 1; t < L; ++t) {
            float4 x2 = px[(size_t)t * (F / 4)];
            ema4(mm, x2);
            qo[(size_t)t * (F / 4)] = pcen4(x2, mm);
        }
    } else {
        float4 mm = *(const float4*)&inbuf[c][f4 * 4];
        #pragma unroll 8
        for (int t = 0; t < L; ++t) {
            float4 x2 = px[(size_t)t * (F / 4)];
            ema4(mm, x2);
            qo[(size_t)t * (F / 4)] = pcen4(x2, mm);
        }
    }
}

extern "C" void kernel_launch(void* const* d_in, const int* in_sizes, int n_in,
                              void* d_out, int out_size, void* d_ws, size_t ws_size,
                              hipStream_t stream) {
    const float* x   = (const float*)d_in[0];
    float*       out = (float*)d_out;
    pcen_kernel<<<dim3(B * (F / FT)), dim3(256), 0, stream>>>(x, out);
}

// Round 4
// 45.872 us; speedup vs baseline: 1.6353x; 1.6353x over previous
//
#include <hip/hip_runtime.h>

// PCEN: EMA over time then (x / (M+eps)^alpha + delta)^r - delta^r
// x: [B=64, T=2048, F=128] float32, out same shape/type.
//
// Exact 3-kernel chunked scan (EMA is affine: m_end = a^L * m_in + local):
//  K1: thread=(b,f,c) computes local chunk carry from 0-init (chunk 0 exact
//      via m[0]=x[0]); f is the lane index -> 256B coalesced wave loads.
//  K2: thread=(b,f) serially composes the 32 chunk carries -> exact carry-in
//      per chunk (2 MB in d_ws).
//  K3: thread=(b,f,c) replays its chunk from the exact carry-in and emits
//      PCEN. x re-read is L3-served (just streamed, 64 MiB << 256 MiB L3).
//
// No warm-up redundancy (R2 lost to 4.5x logical amplification), no in-block
// sequence ownership (R3 lost to scattered wave segments + 2 blocks/CU).

namespace {
constexpr int B = 64;
constexpr int T = 2048;
constexpr int F = 128;
constexpr int CH = 32;        // chunks per sequence
constexpr int L = T / CH;     // 64
constexpr float S   = 0.025f;
constexpr float A1  = 0.975f;
constexpr float AL  = 0.19779136545478059f;  // 0.975^64
constexpr float EPS = 1e-6f;
constexpr float ALPHA = 0.98f;
constexpr float DR  = 1.1892071150027210667f;  // 2^0.25
}

__global__ __launch_bounds__(256) void k_carry(const float* __restrict__ x,
                                               float* __restrict__ carry) {
    const int tid = blockIdx.x * 256 + threadIdx.x;   // [b][c][f], f fastest
    const int f  = tid & (F - 1);
    const int cb = tid >> 7;
    const int c  = cb & (CH - 1);
    const int b  = cb >> 5;

    const float* p = x + ((size_t)(b * T + c * L)) * F + f;
    float m = (c == 0) ? p[0] : 0.0f;   // c==0: update at t=0 re-yields x[0]
    #pragma unroll 8
    for (int t = 0; t < L; ++t) {
        float xv = p[(size_t)t * F];
        m = fmaf(A1, m, S * xv);
    }
    carry[tid] = m;                      // layout [b][c][f]
}

__global__ __launch_bounds__(256) void k_prefix(const float* __restrict__ carry,
                                                float* __restrict__ m_in) {
    const int tid = blockIdx.x * 256 + threadIdx.x;   // 8192 threads: b*F+f
    const int f = tid & (F - 1);
    const int b = tid >> 7;
    const float* cr = carry + (size_t)b * CH * F + f;
    float*       mi = m_in  + (size_t)b * CH * F + f;
    float me = cr[0];                    // exact end of chunk 0
    #pragma unroll
    for (int c = 1; c < CH; ++c) {
        mi[(size_t)c * F] = me;          // carry-in for chunk c
        me = fmaf(AL, me, cr[(size_t)c * F]);
    }
}

__global__ __launch_bounds__(256) void k_final(const float* __restrict__ x,
                                               const float* __restrict__ m_in,
                                               float* __restrict__ out) {
    const int tid = blockIdx.x * 256 + threadIdx.x;
    const int f  = tid & (F - 1);
    const int cb = tid >> 7;
    const int c  = cb & (CH - 1);
    const int b  = cb >> 5;

    const size_t base = ((size_t)(b * T + c * L)) * F + f;
    const float* p = x + base;
    float*       q = out + base;

    float m = (c == 0) ? p[0] : m_in[tid];
    #pragma unroll 8
    for (int t = 0; t < L; ++t) {
        float xv = p[(size_t)t * F];
        m = fmaf(A1, m, S * xv);
        // x / (M+eps)^alpha == x * exp2(-alpha * log2(M+eps))
        float inv = exp2f(-ALPHA * log2f(m + EPS));
        float u   = fmaf(xv, inv, 2.0f);
        q[(size_t)t * F] = sqrtf(sqrtf(u)) - DR;  // u^0.25 - 2^0.25
    }
}

extern "C" void kernel_launch(void* const* d_in, const int* in_sizes, int n_in,
                              void* d_out, int out_size, void* d_ws, size_t ws_size,
                              hipStream_t stream) {
    const float* x   = (const float*)d_in[0];
    float*       out = (float*)d_out;
    float* carry = (float*)d_ws;                       // 1 MiB
    float* m_in  = carry + (size_t)B * CH * F;         // 1 MiB

    const int total = B * CH * F;                      // 262144
    k_carry <<<dim3(total / 256), dim3(256), 0, stream>>>(x, carry);
    k_prefix<<<dim3(B * F / 256), dim3(256), 0, stream>>>(carry, m_in);
    k_final <<<dim3(total / 256), dim3(256), 0, stream>>>(x, m_in, out);
}